// Round 12
// baseline (536.866 us; speedup 1.0000x reference)
//
#include <hip/hip_runtime.h>
#include <math.h>

#define D     64
#define NSLOT 8
#define NB    64
#define NROW  4096
#define NP    16          // row-blocks per batch
#define EPS   1e-5f
#define SCK   (0.125f * 1.44269504f)   // 1/sqrt(64) * 1/ln2 folded into q~ and c

typedef unsigned short ushortt;
typedef __attribute__((ext_vector_type(8))) short bf16x8;
typedef __attribute__((ext_vector_type(4))) short short4v;
typedef __attribute__((ext_vector_type(4))) float f32x4;

__device__ __forceinline__ unsigned short f2bf(float f) {
  return (unsigned short)((__float_as_uint(f) + 0x8000u) >> 16);
}
__device__ __forceinline__ float bf2f(unsigned short v) {
  return __uint_as_float((unsigned)v << 16);
}

__device__ __forceinline__ float wredsum(float v) {
  #pragma unroll
  for (int m = 1; m < 64; m <<= 1) v += __shfl_xor(v, m);
  return v;
}

// Coalesced wave matvec, FULL preload (used only in the small init kernel).
template <int R>
__device__ __forceinline__ void matvec_pre(const float* __restrict__ W,
                                           const float* lin, float* lout,
                                           int lane) {
  const int g = lane >> 4, q = lane & 15;
  float4 w[R >> 2];
  #pragma unroll
  for (int rb = 0; rb < (R >> 2); ++rb)
    w[rb] = *reinterpret_cast<const float4*>(W + (rb * 4 + g) * 64 + 4 * q);
  const float4 iv = *reinterpret_cast<const float4*>(lin + 4 * q);
  #pragma unroll
  for (int rb = 0; rb < (R >> 2); ++rb) {
    float p = w[rb].x * iv.x + w[rb].y * iv.y + w[rb].z * iv.z + w[rb].w * iv.w;
    p += __shfl_xor(p, 1);
    p += __shfl_xor(p, 2);
    p += __shfl_xor(p, 4);
    p += __shfl_xor(p, 8);
    if (q == 0) lout[rb * 4 + g] = p;
  }
}

// Chunked-preload variants (8x float4 = 32 VGPR) for the fused tail.
template <int R>
__device__ __forceinline__ void matvec_mod(const float* __restrict__ W,
                                           const float* lin, float* lout,
                                           int lane) {
  const int g = lane >> 4, q = lane & 15;
  const float4 iv = *reinterpret_cast<const float4*>(lin + 4 * q);
  #pragma unroll
  for (int ch = 0; ch < R / 32; ++ch) {
    float4 w[8];
    #pragma unroll
    for (int i = 0; i < 8; ++i)
      w[i] = *reinterpret_cast<const float4*>(W + (ch * 32 + i * 4 + g) * 64 + 4 * q);
    #pragma unroll
    for (int i = 0; i < 8; ++i) {
      float p = w[i].x * iv.x + w[i].y * iv.y + w[i].z * iv.z + w[i].w * iv.w;
      p += __shfl_xor(p, 1);
      p += __shfl_xor(p, 2);
      p += __shfl_xor(p, 4);
      p += __shfl_xor(p, 8);
      if (q == 0) lout[ch * 32 + i * 4 + g] = p;
    }
  }
}

template <int R>  // C=128
__device__ __forceinline__ void matvec_mod_c128(const float* __restrict__ W,
                                                const float* lin, float* lout,
                                                int lane) {
  const int g = lane >> 4, q = lane & 15;
  const float4 iv0 = *reinterpret_cast<const float4*>(lin + 4 * q);
  const float4 iv1 = *reinterpret_cast<const float4*>(lin + 64 + 4 * q);
  #pragma unroll
  for (int ch = 0; ch < R / 16; ++ch) {
    float4 w0[4], w1[4];
    #pragma unroll
    for (int i = 0; i < 4; ++i) {
      w0[i] = *reinterpret_cast<const float4*>(W + (ch * 16 + i * 4 + g) * 128 + 4 * q);
      w1[i] = *reinterpret_cast<const float4*>(W + (ch * 16 + i * 4 + g) * 128 + 64 + 4 * q);
    }
    #pragma unroll
    for (int i = 0; i < 4; ++i) {
      float p = w0[i].x * iv0.x + w0[i].y * iv0.y + w0[i].z * iv0.z + w0[i].w * iv0.w
              + w1[i].x * iv1.x + w1[i].y * iv1.y + w1[i].z * iv1.z + w1[i].w * iv1.w;
      p += __shfl_xor(p, 1);
      p += __shfl_xor(p, 2);
      p += __shfl_xor(p, 4);
      p += __shfl_xor(p, 8);
      if (q == 0) lout[ch * 16 + i * 4 + g] = p;
    }
  }
}

// ---------------------------------------------------------------------------
// KFUSED: per iteration. kam MFMA pass (r11 body) + atomicAdd U/S partials +
// per-batch counter; the last block of each batch runs the slot-update tail
// (GRU/LN/MLP + next q~/c, or final out) for all 8 slots (2 halves x 4).
// ---------------------------------------------------------------------------
template <int PASS>
__global__ __launch_bounds__(256)
void kfused_kernel(const float* __restrict__ x,
                   ushortt* __restrict__ xnb, int store, int last,
                   float* __restrict__ qtil, float* __restrict__ cvec,
                   float* __restrict__ U, float* __restrict__ S,
                   int* __restrict__ cnt,
                   const float* __restrict__ G, const float* __restrict__ bias_i,
                   const float* __restrict__ Whh, const float* __restrict__ bhh,
                   const float* __restrict__ W1, const float* __restrict__ b1,
                   const float* __restrict__ W2, const float* __restrict__ b2,
                   const float* __restrict__ Mt, const float* __restrict__ ct,
                   const float* __restrict__ u, const float* __restrict__ c0,
                   float* __restrict__ slots, float* __restrict__ out) {
  extern __shared__ char smem[];
  const int b    = blockIdx.x >> 4;
  const int rb   = blockIdx.x & 15;
  const int tid  = threadIdx.x;
  const int w    = tid >> 6;
  const int lane = tid & 63;
  const int sl   = lane & 15;
  const int g    = lane >> 4;

  short* Xdr = (short*)smem + w * (64 * 40);             // [d][r], stride 40
  short* sA  = (short*)(smem + 20480) + w * (16 * 40);   // [s][r], stride 40
  float* lU  = (float*)(smem + 25600);                   // [4][8][64]
  float* lS  = (float*)(smem + 33792);                   // [4][8]
  short* Xrd = (short*)(smem + 33920) + w * (32 * 72);   // PASS1 [r][d], stride 72

  #pragma unroll
  for (int k = 0; k < 10; ++k) sA[k * 64 + lane] = 0;

  bf16x8 qA[2];
  #pragma unroll
  for (int kh = 0; kh < 2; ++kh) {
    if (sl < 8) {
      const float* qp = qtil + (size_t)(b * NSLOT + sl) * D + kh * 32 + g * 8;
      #pragma unroll
      for (int j = 0; j < 8; ++j) qA[kh][j] = (short)f2bf(qp[j]);
    } else {
      #pragma unroll
      for (int j = 0; j < 8; ++j) qA[kh][j] = 0;
    }
  }
  float creg[4];
  #pragma unroll
  for (int r = 0; r < 4; ++r)
    creg[r] = (g < 2) ? cvec[b * NSLOT + 4 * g + r] : 0.f;

  f32x4 C[4];
  #pragma unroll
  for (int nt = 0; nt < 4; ++nt) C[nt] = (f32x4){0.f, 0.f, 0.f, 0.f};
  float Sa[4] = {0.f, 0.f, 0.f, 0.f};

  #pragma unroll
  for (int t = 0; t < 2; ++t) {
    const int tileIdx = (b * NP + rb) * 8 + w * 2 + t;
    bf16x8 Bx[2][2];

    if (PASS == 1) {
      const int rowbase = b * NROW + rb * 256 + w * 64 + t * 32;
      #pragma unroll
      for (int i = 0; i < 8; ++i) {
        const int lr = i * 4 + g;
        const float4 xv =
            reinterpret_cast<const float4*>(x)[(size_t)(rowbase + lr) * 16 + sl];
        float s1 = xv.x + xv.y + xv.z + xv.w;
        float s2 = xv.x * xv.x + xv.y * xv.y + xv.z * xv.z + xv.w * xv.w;
        #pragma unroll
        for (int m = 1; m < 16; m <<= 1) {
          s1 += __shfl_xor(s1, m);
          s2 += __shfl_xor(s2, m);
        }
        float mean = s1 * (1.f / 64.f);
        float var  = s2 * (1.f / 64.f) - mean * mean;
        float rstd = rsqrtf(var + EPS);
        float nb   = -mean * rstd;
        short4v p;
        p[0] = (short)f2bf(fmaf(xv.x, rstd, nb));
        p[1] = (short)f2bf(fmaf(xv.y, rstd, nb));
        p[2] = (short)f2bf(fmaf(xv.z, rstd, nb));
        p[3] = (short)f2bf(fmaf(xv.w, rstd, nb));
        *reinterpret_cast<short4v*>(&Xrd[lr * 72 + 4 * sl]) = p;
      }
      #pragma unroll
      for (int h = 0; h < 2; ++h)
        #pragma unroll
        for (int kh = 0; kh < 2; ++kh) {
          Bx[h][kh] =
              *reinterpret_cast<bf16x8*>(&Xrd[(h * 16 + sl) * 72 + kh * 32 + g * 8]);
          if (store)
            reinterpret_cast<bf16x8*>(xnb)[((size_t)tileIdx * 4 + h * 2 + kh) * 64 + lane] =
                Bx[h][kh];
        }
    } else {
      #pragma unroll
      for (int h = 0; h < 2; ++h)
        #pragma unroll
        for (int kh = 0; kh < 2; ++kh)
          Bx[h][kh] = reinterpret_cast<const bf16x8*>(
              xnb)[((size_t)tileIdx * 4 + h * 2 + kh) * 64 + lane];
    }

    #pragma unroll
    for (int h = 0; h < 2; ++h)
      #pragma unroll
      for (int kh = 0; kh < 2; ++kh)
        #pragma unroll
        for (int j = 0; j < 8; ++j)
          Xdr[(kh * 32 + g * 8 + j) * 40 + h * 16 + sl] = Bx[h][kh][j];

    #pragma unroll
    for (int h = 0; h < 2; ++h) {
      f32x4 Dh = (f32x4){0.f, 0.f, 0.f, 0.f};
      Dh = __builtin_amdgcn_mfma_f32_16x16x32_bf16(qA[0], Bx[h][0], Dh, 0, 0, 0);
      Dh = __builtin_amdgcn_mfma_f32_16x16x32_bf16(qA[1], Bx[h][1], Dh, 0, 0, 0);
      float e[4];
      float z = 0.f;
      #pragma unroll
      for (int r = 0; r < 4; ++r) {
        e[r] = (g < 2) ? exp2f(Dh[r] + creg[r]) : 0.f;
        z += e[r];
      }
      z += __shfl_xor(z, 16);
      float inv = 1.f / z;
      #pragma unroll
      for (int r = 0; r < 4; ++r) {
        float a = e[r] * inv + 1e-8f;
        unsigned short ab = f2bf(a);
        Sa[r] += bf2f(ab);
        if (g < 2) sA[(4 * g + r) * 40 + h * 16 + sl] = (short)ab;
      }
    }

    bf16x8 aF = *reinterpret_cast<bf16x8*>(&sA[sl * 40 + g * 8]);
    #pragma unroll
    for (int nt = 0; nt < 4; ++nt) {
      bf16x8 bF = *reinterpret_cast<bf16x8*>(&Xdr[(nt * 16 + sl) * 40 + g * 8]);
      C[nt] = __builtin_amdgcn_mfma_f32_16x16x32_bf16(aF, bF, C[nt], 0, 0, 0);
    }
  }

  if (g < 2) {
    #pragma unroll
    for (int nt = 0; nt < 4; ++nt)
      #pragma unroll
      for (int r = 0; r < 4; ++r)
        lU[(w * NSLOT + 4 * g + r) * D + nt * 16 + sl] = C[nt][r];
  }
  #pragma unroll
  for (int r = 0; r < 4; ++r) {
    #pragma unroll
    for (int m = 1; m < 16; m <<= 1) Sa[r] += __shfl_xor(Sa[r], m);
  }
  if (g < 2 && sl == 0) {
    #pragma unroll
    for (int r = 0; r < 4; ++r) lS[w * NSLOT + 4 * g + r] = Sa[r];
  }
  __syncthreads();

  for (int cell = tid; cell < NSLOT * D; cell += 256) {
    int s = cell >> 6, d2 = cell & 63;
    atomicAdd(&U[(b * NSLOT + s) * D + d2],
              lU[(0 * NSLOT + s) * D + d2] + lU[(1 * NSLOT + s) * D + d2] +
              lU[(2 * NSLOT + s) * D + d2] + lU[(3 * NSLOT + s) * D + d2]);
  }
  if (tid < NSLOT)
    atomicAdd(&S[b * NSLOT + tid],
              lS[0 * NSLOT + tid] + lS[1 * NSLOT + tid] +
              lS[2 * NSLOT + tid] + lS[3 * NSLOT + tid]);

  // ---- per-batch completion handshake ----
  __syncthreads();          // drains each wave's vmcnt -> block atomics done
  __shared__ int lastFlag;
  if (tid == 0) {
    __threadfence();
    lastFlag = (atomicAdd(&cnt[b], 1) == NP - 1) ? 1 : 0;
  }
  __syncthreads();
  if (!lastFlag) return;

  // ---- tail: slot update for batch b (2 halves x 4 slots) ----
  float* tb   = (float*)smem;
  const int half = tid >> 7;
  const int wv2  = (tid >> 6) & 1;
  const int dd   = tid & 63;
  const int lt   = tid & 127;
  float* bufA = tb + half * 576;
  float* gi   = bufA + 64;
  float* gh   = gi + 192;
  float* bufH = gh + 192;   // 128

  for (int so = 0; so < 4; ++so) {
    const int s   = half * 4 + so;
    const int idx = (b * NSLOT + s) * D + dd;
    float h = 0.f, slv = 0.f;
    if (wv2 == 0) {
      float Uv = __hip_atomic_load(&U[idx], __ATOMIC_RELAXED, __HIP_MEMORY_SCOPE_AGENT);
      float Ss = __hip_atomic_load(&S[b * NSLOT + s], __ATOMIC_RELAXED, __HIP_MEMORY_SCOPE_AGENT);
      if (!last) {
        U[idx] = 0.f;
        if (dd == 0) S[b * NSLOT + s] = 0.f;
      }
      bufA[dd] = Uv / Ss;
      h = slots[idx];
      bufH[dd] = h;
    }
    __syncthreads();
    if (wv2 == 0) matvec_mod<192>(G,   bufA, gi, dd);
    else          matvec_mod<192>(Whh, bufH, gh, dd);
    __syncthreads();
    if (wv2 == 0) {
      float r  = 1.f / (1.f + expf(-(gi[dd]       + bias_i[dd]       + gh[dd]       + bhh[dd])));
      float z  = 1.f / (1.f + expf(-(gi[64 + dd]  + bias_i[64 + dd]  + gh[64 + dd]  + bhh[64 + dd])));
      float nn = tanhf(gi[128 + dd] + bias_i[128 + dd] + r * (gh[128 + dd] + bhh[128 + dd]));
      h = (1.f - z) * nn + z * h;
      float m  = wredsum(h) * (1.f / 64.f);
      float hc = h - m;
      float v  = wredsum(hc * hc) * (1.f / 64.f);
      slv = hc * rsqrtf(v + EPS);
      bufA[dd] = slv;
    }
    __syncthreads();
    matvec_mod<64>(W1 + wv2 * 64 * 64, bufA, gi + wv2 * 64, dd);
    __syncthreads();
    bufH[lt] = fmaxf(gi[lt] + b1[lt], 0.f);
    __syncthreads();
    matvec_mod_c128<32>(W2 + wv2 * 32 * 128, bufH, gh + wv2 * 32, dd);
    __syncthreads();
    if (wv2 == 0) {
      h = slv + gh[dd] + b2[dd];
      slots[idx] = h;
      if (last) out[idx] = h;
    }
    if (!last) {
      if (wv2 == 0) {
        float m  = wredsum(h) * (1.f / 64.f);
        float hc = h - m;
        float v  = wredsum(hc * hc) * (1.f / 64.f);
        float ln = hc * rsqrtf(v + EPS);
        bufA[dd] = ln;
      }
      __syncthreads();
      matvec_mod<32>(Mt + wv2 * 32 * 64, bufA, gi + wv2 * 32, dd);
      __syncthreads();
      if (wv2 == 0) {
        qtil[idx] = SCK * (gi[dd] + ct[dd]);
        float ca = (wredsum(u[dd] * bufA[dd]) + c0[0]) * SCK;
        if (dd == 0) cvec[b * NSLOT + s] = ca;
      }
    }
    __syncthreads();
  }
}

// ---------------------------------------------------------------------------
// prep work (4 extra blocks on the init launch)
// ---------------------------------------------------------------------------
__device__ void prep_block(int pb,
                           const float* __restrict__ Wq, const float* __restrict__ bq,
                           const float* __restrict__ Wk, const float* __restrict__ bk,
                           const float* __restrict__ Wv, const float* __restrict__ bv,
                           const float* __restrict__ Wih, const float* __restrict__ bih,
                           float* __restrict__ Mt, float* __restrict__ ct,
                           float* __restrict__ u, float* __restrict__ c0,
                           float* __restrict__ G, float* __restrict__ bias_i) {
  const int t = threadIdx.x;  // 0..127
  float acc[32];
  #pragma unroll
  for (int j = 0; j < 32; ++j) acc[j] = 0.f;
  if (pb == 0) {
    const int row = t >> 1;
    const int cb  = (t & 1) * 32;
    for (int f = 0; f < 64; ++f) {
      float wkf = Wk[f * 64 + row];
      const float4* wq4 = reinterpret_cast<const float4*>(Wq + f * 64 + cb);
      #pragma unroll
      for (int j4 = 0; j4 < 8; ++j4) {
        float4 wq = wq4[j4];
        acc[4 * j4 + 0] = fmaf(wkf, wq.x, acc[4 * j4 + 0]);
        acc[4 * j4 + 1] = fmaf(wkf, wq.y, acc[4 * j4 + 1]);
        acc[4 * j4 + 2] = fmaf(wkf, wq.z, acc[4 * j4 + 2]);
        acc[4 * j4 + 3] = fmaf(wkf, wq.w, acc[4 * j4 + 3]);
      }
    }
    #pragma unroll
    for (int j = 0; j < 32; ++j) Mt[row * 64 + cb + j] = acc[j];
    if (t < 64) {
      float a = 0.f, bsum = 0.f;
      for (int f = 0; f < 64; ++f) {
        a    = fmaf(bq[f], Wk[f * 64 + t], a);
        bsum = fmaf(bk[f], Wq[f * 64 + t], bsum);
      }
      ct[t] = a;
      u[t]  = bsum;
    }
    if (t == 0) {
      float a = 0.f;
      for (int f = 0; f < 64; ++f) a = fmaf(bk[f], bq[f], a);
      c0[0] = a;
    }
  } else {
    const int r0  = (pb - 1) * 64;
    const int row = r0 + (t >> 1);
    const int cb  = (t & 1) * 32;
    for (int f = 0; f < 64; ++f) {
      float wih = Wih[row * 64 + f];
      const float4* wv4 = reinterpret_cast<const float4*>(Wv + f * 64 + cb);
      #pragma unroll
      for (int j4 = 0; j4 < 8; ++j4) {
        float4 wv = wv4[j4];
        acc[4 * j4 + 0] = fmaf(wih, wv.x, acc[4 * j4 + 0]);
        acc[4 * j4 + 1] = fmaf(wih, wv.y, acc[4 * j4 + 1]);
        acc[4 * j4 + 2] = fmaf(wih, wv.z, acc[4 * j4 + 2]);
        acc[4 * j4 + 3] = fmaf(wih, wv.w, acc[4 * j4 + 3]);
      }
    }
    #pragma unroll
    for (int j = 0; j < 32; ++j) G[row * 64 + cb + j] = acc[j];
    if (t < 64) {
      int rr = r0 + t;
      float a = bih[rr];
      for (int f = 0; f < 64; ++f) a = fmaf(Wih[rr * 64 + f], bv[f], a);
      bias_i[rr] = a;
    }
  }
}

// ---------------------------------------------------------------------------
// KINIT: per-(batch,slot) init (slots, q~ unfolded, zero U/S) + cnt zero +
// prep blocks. 128 threads; only wave 0 does slot work.
// ---------------------------------------------------------------------------
__global__ __launch_bounds__(128, 1)
void kinit_kernel(const float* __restrict__ noise, const float* __restrict__ mu,
                  const float* __restrict__ sigma,
                  const float* __restrict__ Wq, const float* __restrict__ bq,
                  const float* __restrict__ Wk, const float* __restrict__ bk,
                  const float* __restrict__ Wv, const float* __restrict__ bv,
                  const float* __restrict__ Wih, const float* __restrict__ bih,
                  float* __restrict__ Mt, float* __restrict__ ct,
                  float* __restrict__ u, float* __restrict__ c0,
                  float* __restrict__ G, float* __restrict__ bias_i,
                  float* __restrict__ slots, float* __restrict__ qtil,
                  float* __restrict__ cvec, float* __restrict__ U,
                  float* __restrict__ S, int* __restrict__ cnt) {
  if (blockIdx.x >= NB * NSLOT) {
    prep_block(blockIdx.x - NB * NSLOT, Wq, bq, Wk, bk, Wv, bv, Wih, bih,
               Mt, ct, u, c0, G, bias_i);
    return;
  }
  const int blk = blockIdx.x;
  const int b   = blk >> 3;
  const int s   = blk & 7;
  const int wv  = threadIdx.x >> 6;
  const int d   = threadIdx.x & 63;
  const int idx = (b * NSLOT + s) * D + d;

  if (blk == 0) {
    cnt[threadIdx.x] = 0;
    if (threadIdx.x < 64) cnt[128 + threadIdx.x] = 0;
  }

  __shared__ float bufA[64];
  __shared__ float bufQ[64];
  __shared__ float gi[192];

  if (wv == 0) {
    float h = mu[d] + sigma[d] * noise[idx];
    slots[idx] = h;
    U[idx] = 0.f;
    if (d == 0) S[b * NSLOT + s] = 0.f;
    float m  = wredsum(h) * (1.f / 64.f);
    float hc = h - m;
    float v  = wredsum(hc * hc) * (1.f / 64.f);
    float ln = hc * rsqrtf(v + EPS);
    bufA[d] = ln;
    matvec_pre<64>(Wq, bufA, gi, d);
    float qv = gi[d] + bq[d];
    bufQ[d] = qv;
    float qt0 = 0.f, qt1 = 0.f, qt2 = 0.f, qt3 = 0.f;
    #pragma unroll
    for (int e = 0; e < 64; e += 4) {
      const float4 qb = *reinterpret_cast<const float4*>(bufQ + e);
      qt0 = fmaf(Wk[(e + 0) * D + d], qb.x, qt0);
      qt1 = fmaf(Wk[(e + 1) * D + d], qb.y, qt1);
      qt2 = fmaf(Wk[(e + 2) * D + d], qb.z, qt2);
      qt3 = fmaf(Wk[(e + 3) * D + d], qb.w, qt3);
    }
    qtil[idx] = ((qt0 + qt1) + (qt2 + qt3)) * SCK;
    float ca = wredsum(bk[d] * qv) * SCK;
    if (d == 0) cvec[b * NSLOT + s] = ca;
  }
}

// ---------------------------------------------------------------------------
extern "C" void kernel_launch(void* const* d_in, const int* in_sizes, int n_in,
                              void* d_out, int out_size, void* d_ws, size_t ws_size,
                              hipStream_t stream) {
  (void)in_sizes; (void)n_in; (void)out_size;
  const float* x     = (const float*)d_in[0];
  const float* noise = (const float*)d_in[1];
  const float* Wq    = (const float*)d_in[2];
  const float* bq    = (const float*)d_in[3];
  const float* Wk    = (const float*)d_in[4];
  const float* bk    = (const float*)d_in[5];
  const float* Wv    = (const float*)d_in[6];
  const float* bv    = (const float*)d_in[7];
  const float* Wih   = (const float*)d_in[8];
  const float* Whh   = (const float*)d_in[9];
  const float* bih   = (const float*)d_in[10];
  const float* bhh   = (const float*)d_in[11];
  const float* W1    = (const float*)d_in[12];
  const float* b1    = (const float*)d_in[13];
  const float* W2    = (const float*)d_in[14];
  const float* b2    = (const float*)d_in[15];
  const float* mu    = (const float*)d_in[16];
  const float* sigma = (const float*)d_in[17];

  float* ws     = (float*)d_ws;
  float* slots  = ws;           // 32768
  float* qtil   = ws + 32768;   // 32768
  float* cvec   = ws + 65536;   // 512
  float* Mt     = ws + 66048;   // 4096
  float* ct     = ws + 70144;   // 64
  float* uvec   = ws + 70208;   // 64
  float* c0     = ws + 70272;   // 16
  float* G      = ws + 70288;   // 12288
  float* bias_i = ws + 82576;   // 192
  int*   cnt    = (int*)(ws + 82768);  // 3*64 ints
  float* U      = ws + 83008;   // 32768
  float* S      = ws + 115776;  // 512 -> end 116288
  ushortt* xnb  = (ushortt*)(ws + 615296);  // 33.5 MB
  float* out    = (float*)d_out;

  const bool use_xnb = ws_size >= (size_t)(615296 + 8388608) * sizeof(float);

  const int SM1 = 52352;  // Xdr+sA+lU+lS+Xrd
  const int SM2 = 33920;  // Xdr+sA+lU+lS

  kinit_kernel<<<NB * NSLOT + 4, 128, 0, stream>>>(
      noise, mu, sigma, Wq, bq, Wk, bk, Wv, bv, Wih, bih,
      Mt, ct, uvec, c0, G, bias_i, slots, qtil, cvec, U, S, cnt);

  for (int it = 1; it <= 3; ++it) {
    int last = (it == 3) ? 1 : 0;
    int* cntI = cnt + (it - 1) * NB;
    if (!use_xnb) {
      kfused_kernel<1><<<NB * NP, 256, SM1, stream>>>(
          x, xnb, 0, last, qtil, cvec, U, S, cntI, G, bias_i, Whh, bhh,
          W1, b1, W2, b2, Mt, ct, uvec, c0, slots, out);
    } else if (it == 1) {
      kfused_kernel<1><<<NB * NP, 256, SM1, stream>>>(
          x, xnb, 1, last, qtil, cvec, U, S, cntI, G, bias_i, Whh, bhh,
          W1, b1, W2, b2, Mt, ct, uvec, c0, slots, out);
    } else {
      kfused_kernel<2><<<NB * NP, 256, SM2, stream>>>(
          x, xnb, 0, last, qtil, cvec, U, S, cntI, G, bias_i, Whh, bhh,
          W1, b1, W2, b2, Mt, ct, uvec, c0, slots, out);
    }
  }
}

// Round 13
// 122.465 us; speedup vs baseline: 4.3838x; 4.3838x over previous
//
#include <hip/hip_runtime.h>
#include <math.h>

#define D     64
#define NSLOT 8
#define NB    64
#define NROW  4096
#define NP    16          // row-blocks (partials) per batch
#define EPS   1e-5f
#define SCK   (0.125f * 1.44269504f)   // 1/sqrt(64) * 1/ln2 folded into q~ and c

typedef unsigned short ushortt;
typedef __attribute__((ext_vector_type(8))) short bf16x8;
typedef __attribute__((ext_vector_type(4))) short short4v;
typedef __attribute__((ext_vector_type(4))) float f32x4;

__device__ __forceinline__ unsigned short f2bf(float f) {
  return (unsigned short)((__float_as_uint(f) + 0x8000u) >> 16);
}
__device__ __forceinline__ float bf2f(unsigned short v) {
  return __uint_as_float((unsigned)v << 16);
}

__device__ __forceinline__ float wredsum(float v) {
  #pragma unroll
  for (int m = 1; m < 64; m <<= 1) v += __shfl_xor(v, m);
  return v;
}

// Coalesced wave matvec, full register preload: out[r] = W[r,:].lin, C=64.
template <int R>
__device__ __forceinline__ void matvec_pre(const float* __restrict__ W,
                                           const float* lin, float* lout,
                                           int lane) {
  const int g = lane >> 4, q = lane & 15;
  float4 w[R >> 2];
  #pragma unroll
  for (int rb = 0; rb < (R >> 2); ++rb)
    w[rb] = *reinterpret_cast<const float4*>(W + (rb * 4 + g) * 64 + 4 * q);
  const float4 iv = *reinterpret_cast<const float4*>(lin + 4 * q);
  #pragma unroll
  for (int rb = 0; rb < (R >> 2); ++rb) {
    float p = w[rb].x * iv.x + w[rb].y * iv.y + w[rb].z * iv.z + w[rb].w * iv.w;
    p += __shfl_xor(p, 1);
    p += __shfl_xor(p, 2);
    p += __shfl_xor(p, 4);
    p += __shfl_xor(p, 8);
    if (q == 0) lout[rb * 4 + g] = p;
  }
}

template <int R>
__device__ __forceinline__ void matvec_pre_c128(const float* __restrict__ W,
                                                const float* lin, float* lout,
                                                int lane) {
  const int g = lane >> 4, q = lane & 15;
  float4 w0[R >> 2], w1[R >> 2];
  #pragma unroll
  for (int rb = 0; rb < (R >> 2); ++rb) {
    w0[rb] = *reinterpret_cast<const float4*>(W + (rb * 4 + g) * 128 + 4 * q);
    w1[rb] = *reinterpret_cast<const float4*>(W + (rb * 4 + g) * 128 + 64 + 4 * q);
  }
  const float4 iv0 = *reinterpret_cast<const float4*>(lin + 4 * q);
  const float4 iv1 = *reinterpret_cast<const float4*>(lin + 64 + 4 * q);
  #pragma unroll
  for (int rb = 0; rb < (R >> 2); ++rb) {
    float p = w0[rb].x * iv0.x + w0[rb].y * iv0.y + w0[rb].z * iv0.z + w0[rb].w * iv0.w
            + w1[rb].x * iv1.x + w1[rb].y * iv1.y + w1[rb].z * iv1.z + w1[rb].w * iv1.w;
    p += __shfl_xor(p, 1);
    p += __shfl_xor(p, 2);
    p += __shfl_xor(p, 4);
    p += __shfl_xor(p, 8);
    if (q == 0) lout[rb * 4 + g] = p;
  }
}

// ---------------------------------------------------------------------------
// KAM: MFMA pass over x (r11 body). r13 change: PASS=2 prefetches BOTH tiles'
// xnb fragments into registers up front, so tile 1's HBM latency hides under
// tile 0's LDS/MFMA/softmax processing (wave was latency-serialized before).
// PASS=1 (LN + bf16 store path) untouched.
// ---------------------------------------------------------------------------
template <int PASS>
__global__ __launch_bounds__(256)
void kam_kernel(const float* __restrict__ x,
                ushortt* __restrict__ xnb, int store,
                const float* __restrict__ qtil,
                const float* __restrict__ cvec,
                float* __restrict__ Up, float* __restrict__ Sp) {
  extern __shared__ char smem[];
  const int b    = blockIdx.x >> 4;
  const int rb   = blockIdx.x & 15;
  const int tid  = threadIdx.x;
  const int w    = tid >> 6;
  const int lane = tid & 63;
  const int sl   = lane & 15;
  const int g    = lane >> 4;

  short* Xdr = (short*)smem + w * (64 * 40);             // [d][r], stride 40
  short* sA  = (short*)(smem + 20480) + w * (16 * 40);   // [s][r], stride 40
  float* lU  = (float*)(smem + 25600);                   // [4][8][64]
  float* lS  = (float*)(smem + 33792);                   // [4][8]
  short* Xrd = (short*)(smem + 33920) + w * (32 * 72);   // PASS1 [r][d], stride 72

  // zero sA once: rows s=8..15 stay zero (A-operand padding)
  #pragma unroll
  for (int k = 0; k < 10; ++k) sA[k * 64 + lane] = 0;

  // q~ A-fragments (bf16; slots 8..15 zero). A[m][k]: m=lane&15, k=(lane>>4)*8+j
  bf16x8 qA[2];
  #pragma unroll
  for (int kh = 0; kh < 2; ++kh) {
    if (sl < 8) {
      const float* qp = qtil + (size_t)(b * NSLOT + sl) * D + kh * 32 + g * 8;
      #pragma unroll
      for (int j = 0; j < 8; ++j) qA[kh][j] = (short)f2bf(qp[j]);
    } else {
      #pragma unroll
      for (int j = 0; j < 8; ++j) qA[kh][j] = 0;
    }
  }
  float creg[4];
  #pragma unroll
  for (int r = 0; r < 4; ++r)
    creg[r] = (g < 2) ? cvec[b * NSLOT + 4 * g + r] : 0.f;

  f32x4 C[4];
  #pragma unroll
  for (int nt = 0; nt < 4; ++nt) C[nt] = (f32x4){0.f, 0.f, 0.f, 0.f};
  float Sa[4] = {0.f, 0.f, 0.f, 0.f};

  // r13: PASS2 prefetch of both tiles' fragments (registers; +~16-32 VGPR)
  bf16x8 BxAll[2][2][2];
  if (PASS == 2) {
    #pragma unroll
    for (int t = 0; t < 2; ++t) {
      const int tileIdx = (b * NP + rb) * 8 + w * 2 + t;
      #pragma unroll
      for (int h = 0; h < 2; ++h)
        #pragma unroll
        for (int kh = 0; kh < 2; ++kh)
          BxAll[t][h][kh] = reinterpret_cast<const bf16x8*>(
              xnb)[((size_t)tileIdx * 4 + h * 2 + kh) * 64 + lane];
    }
  }

  #pragma unroll
  for (int t = 0; t < 2; ++t) {
    const int tileIdx = (b * NP + rb) * 8 + w * 2 + t;   // 32-row tiles, global id
    bf16x8 Bx[2][2];

    if (PASS == 1) {
      const int rowbase = b * NROW + rb * 256 + w * 64 + t * 32;
      #pragma unroll
      for (int i = 0; i < 8; ++i) {
        const int lr = i * 4 + g;
        const float4 xv =
            reinterpret_cast<const float4*>(x)[(size_t)(rowbase + lr) * 16 + sl];
        float s1 = xv.x + xv.y + xv.z + xv.w;
        float s2 = xv.x * xv.x + xv.y * xv.y + xv.z * xv.z + xv.w * xv.w;
        #pragma unroll
        for (int m = 1; m < 16; m <<= 1) {
          s1 += __shfl_xor(s1, m);
          s2 += __shfl_xor(s2, m);
        }
        float mean = s1 * (1.f / 64.f);
        float var  = s2 * (1.f / 64.f) - mean * mean;
        float rstd = rsqrtf(var + EPS);
        float nb   = -mean * rstd;
        short4v p;
        p[0] = (short)f2bf(fmaf(xv.x, rstd, nb));
        p[1] = (short)f2bf(fmaf(xv.y, rstd, nb));
        p[2] = (short)f2bf(fmaf(xv.z, rstd, nb));
        p[3] = (short)f2bf(fmaf(xv.w, rstd, nb));
        *reinterpret_cast<short4v*>(&Xrd[lr * 72 + 4 * sl]) = p;
      }
      #pragma unroll
      for (int h = 0; h < 2; ++h)
        #pragma unroll
        for (int kh = 0; kh < 2; ++kh) {
          Bx[h][kh] =
              *reinterpret_cast<bf16x8*>(&Xrd[(h * 16 + sl) * 72 + kh * 32 + g * 8]);
          if (store)
            reinterpret_cast<bf16x8*>(xnb)[((size_t)tileIdx * 4 + h * 2 + kh) * 64 + lane] =
                Bx[h][kh];
        }
    } else {
      #pragma unroll
      for (int h = 0; h < 2; ++h)
        #pragma unroll
        for (int kh = 0; kh < 2; ++kh)
          Bx[h][kh] = BxAll[t][h][kh];
    }

    // scatter xn -> Xdr [d][r]  (lane holds row h*16+sl, d = kh*32+g*8+j)
    #pragma unroll
    for (int h = 0; h < 2; ++h)
      #pragma unroll
      for (int kh = 0; kh < 2; ++kh)
        #pragma unroll
        for (int j = 0; j < 8; ++j)
          Xdr[(kh * 32 + g * 8 + j) * 40 + h * 16 + sl] = Bx[h][kh][j];

    // logits + softmax + attn^T pack, per 16-row half
    #pragma unroll
    for (int h = 0; h < 2; ++h) {
      f32x4 Dh = (f32x4){0.f, 0.f, 0.f, 0.f};
      Dh = __builtin_amdgcn_mfma_f32_16x16x32_bf16(qA[0], Bx[h][0], Dh, 0, 0, 0);
      Dh = __builtin_amdgcn_mfma_f32_16x16x32_bf16(qA[1], Bx[h][1], Dh, 0, 0, 0);
      // lane: row r = sl, slots s = 4*g+reg (valid g<2). log2-domain, no max-sub.
      float e[4];
      float z = 0.f;
      #pragma unroll
      for (int r = 0; r < 4; ++r) {
        e[r] = (g < 2) ? exp2f(Dh[r] + creg[r]) : 0.f;
        z += e[r];
      }
      z += __shfl_xor(z, 16);   // combine slot-groups 0+1
      float inv = 1.f / z;
      #pragma unroll
      for (int r = 0; r < 4; ++r) {
        float a = e[r] * inv + 1e-8f;
        unsigned short ab = f2bf(a);
        Sa[r] += bf2f(ab);      // same rounded value as used in MFMA
        if (g < 2) sA[(4 * g + r) * 40 + h * 16 + sl] = (short)ab;
      }
    }

    // update MFMAs: A = attn^T [s][r], B = Xn [r][d]
    bf16x8 aF = *reinterpret_cast<bf16x8*>(&sA[sl * 40 + g * 8]);
    #pragma unroll
    for (int nt = 0; nt < 4; ++nt) {
      bf16x8 bF = *reinterpret_cast<bf16x8*>(&Xdr[(nt * 16 + sl) * 40 + g * 8]);
      C[nt] = __builtin_amdgcn_mfma_f32_16x16x32_bf16(aF, bF, C[nt], 0, 0, 0);
    }
  }

  // epilogue: D[m=s][n=d]: lane holds d = nt*16+sl, s = 4*g+reg (valid g<2)
  if (g < 2) {
    #pragma unroll
    for (int nt = 0; nt < 4; ++nt)
      #pragma unroll
      for (int r = 0; r < 4; ++r)
        lU[(w * NSLOT + 4 * g + r) * D + nt * 16 + sl] = C[nt][r];
  }
  #pragma unroll
  for (int r = 0; r < 4; ++r) {
    #pragma unroll
    for (int m = 1; m < 16; m <<= 1) Sa[r] += __shfl_xor(Sa[r], m);
  }
  if (g < 2 && sl == 0) {
    #pragma unroll
    for (int r = 0; r < 4; ++r) lS[w * NSLOT + 4 * g + r] = Sa[r];
  }
  __syncthreads();

  for (int cell = tid; cell < NSLOT * D; cell += 256) {
    int s = cell >> 6, d = cell & 63;
    Up[((size_t)(b * NSLOT + s) * NP + rb) * D + d] =
        lU[(0 * NSLOT + s) * D + d] + lU[(1 * NSLOT + s) * D + d] +
        lU[(2 * NSLOT + s) * D + d] + lU[(3 * NSLOT + s) * D + d];
  }
  if (tid < NSLOT)
    Sp[(b * NSLOT + tid) * NP + rb] =
        lS[0 * NSLOT + tid] + lS[1 * NSLOT + tid] +
        lS[2 * NSLOT + tid] + lS[3 * NSLOT + tid];
}

// ---------------------------------------------------------------------------
// prep work (4 blocks of 128 thr, appended to the mode-0 kb launch)
// ---------------------------------------------------------------------------
__device__ void prep_block(int pb,
                           const float* __restrict__ Wq, const float* __restrict__ bq,
                           const float* __restrict__ Wk, const float* __restrict__ bk,
                           const float* __restrict__ Wv, const float* __restrict__ bv,
                           const float* __restrict__ Wih, const float* __restrict__ bih,
                           float* __restrict__ Mt, float* __restrict__ ct,
                           float* __restrict__ u, float* __restrict__ c0,
                           float* __restrict__ G, float* __restrict__ bias_i) {
  const int t = threadIdx.x;  // 0..127
  float acc[32];
  #pragma unroll
  for (int j = 0; j < 32; ++j) acc[j] = 0.f;
  if (pb == 0) {
    const int row = t >> 1;
    const int cb  = (t & 1) * 32;
    for (int f = 0; f < 64; ++f) {
      float wkf = Wk[f * 64 + row];
      const float4* wq4 = reinterpret_cast<const float4*>(Wq + f * 64 + cb);
      #pragma unroll
      for (int j4 = 0; j4 < 8; ++j4) {
        float4 wq = wq4[j4];
        acc[4 * j4 + 0] = fmaf(wkf, wq.x, acc[4 * j4 + 0]);
        acc[4 * j4 + 1] = fmaf(wkf, wq.y, acc[4 * j4 + 1]);
        acc[4 * j4 + 2] = fmaf(wkf, wq.z, acc[4 * j4 + 2]);
        acc[4 * j4 + 3] = fmaf(wkf, wq.w, acc[4 * j4 + 3]);
      }
    }
    #pragma unroll
    for (int j = 0; j < 32; ++j) Mt[row * 64 + cb + j] = acc[j];
    if (t < 64) {
      float a = 0.f, bsum = 0.f;
      for (int f = 0; f < 64; ++f) {
        a    = fmaf(bq[f], Wk[f * 64 + t], a);
        bsum = fmaf(bk[f], Wq[f * 64 + t], bsum);
      }
      ct[t] = a;
      u[t]  = bsum;
    }
    if (t == 0) {
      float a = 0.f;
      for (int f = 0; f < 64; ++f) a = fmaf(bk[f], bq[f], a);
      c0[0] = a;
    }
  } else {
    const int r0  = (pb - 1) * 64;
    const int row = r0 + (t >> 1);
    const int cb  = (t & 1) * 32;
    for (int f = 0; f < 64; ++f) {
      float wih = Wih[row * 64 + f];
      const float4* wv4 = reinterpret_cast<const float4*>(Wv + f * 64 + cb);
      #pragma unroll
      for (int j4 = 0; j4 < 8; ++j4) {
        float4 wv = wv4[j4];
        acc[4 * j4 + 0] = fmaf(wih, wv.x, acc[4 * j4 + 0]);
        acc[4 * j4 + 1] = fmaf(wih, wv.y, acc[4 * j4 + 1]);
        acc[4 * j4 + 2] = fmaf(wih, wv.z, acc[4 * j4 + 2]);
        acc[4 * j4 + 3] = fmaf(wih, wv.w, acc[4 * j4 + 3]);
      }
    }
    #pragma unroll
    for (int j = 0; j < 32; ++j) G[row * 64 + cb + j] = acc[j];
    if (t < 64) {
      int rr = r0 + t;
      float a = bih[rr];
      for (int f = 0; f < 64; ++f) a = fmaf(Wih[rr * 64 + f], bv[f], a);
      bias_i[rr] = a;
    }
  }
}

// ---------------------------------------------------------------------------
// KB: per-(batch,slot), 128 threads = 2 waves (unchanged from r11).
// ---------------------------------------------------------------------------
__global__ __launch_bounds__(128, 1)
void kb_kernel(int mode, int last,
               const float* __restrict__ noise, const float* __restrict__ mu,
               const float* __restrict__ sigma,
               const float* __restrict__ Wq, const float* __restrict__ bq,
               const float* __restrict__ Wk, const float* __restrict__ bk,
               const float* __restrict__ Wv, const float* __restrict__ bv,
               const float* __restrict__ Wih, const float* __restrict__ bih,
               float* __restrict__ G, float* __restrict__ bias_i,
               const float* __restrict__ Whh, const float* __restrict__ bhh,
               const float* __restrict__ W1, const float* __restrict__ b1,
               const float* __restrict__ W2, const float* __restrict__ b2,
               float* __restrict__ Mt, float* __restrict__ ct,
               float* __restrict__ u, float* __restrict__ c0,
               float* __restrict__ slots, float* __restrict__ qtil,
               float* __restrict__ cvec, const float* __restrict__ Up,
               const float* __restrict__ Sp, float* __restrict__ out) {
  if (blockIdx.x >= NB * NSLOT) {  // prep blocks (mode-0 launch only)
    prep_block(blockIdx.x - NB * NSLOT, Wq, bq, Wk, bk, Wv, bv, Wih, bih,
               Mt, ct, u, c0, G, bias_i);
    return;
  }

  const int blk = blockIdx.x;
  const int b   = blk >> 3;
  const int s   = blk & 7;
  const int wv  = threadIdx.x >> 6;
  const int d   = threadIdx.x & 63;
  const int idx = (b * NSLOT + s) * D + d;

  __shared__ float bufA[64];
  __shared__ float bufQ[64];
  __shared__ float gi[192];
  __shared__ float gh[192];
  __shared__ float bufH[128];

  if (mode == 0) {
    if (wv == 0) {
      float h = mu[d] + sigma[d] * noise[idx];
      slots[idx] = h;
      float m  = wredsum(h) * (1.f / 64.f);
      float hc = h - m;
      float v  = wredsum(hc * hc) * (1.f / 64.f);
      float ln = hc * rsqrtf(v + EPS);
      bufA[d] = ln;
      matvec_pre<64>(Wq, bufA, gi, d);
      float qv = gi[d] + bq[d];
      bufQ[d] = qv;
      float qt0 = 0.f, qt1 = 0.f, qt2 = 0.f, qt3 = 0.f;
      #pragma unroll
      for (int e = 0; e < 64; e += 4) {
        const float4 qb = *reinterpret_cast<const float4*>(bufQ + e);
        qt0 = fmaf(Wk[(e + 0) * D + d], qb.x, qt0);
        qt1 = fmaf(Wk[(e + 1) * D + d], qb.y, qt1);
        qt2 = fmaf(Wk[(e + 2) * D + d], qb.z, qt2);
        qt3 = fmaf(Wk[(e + 3) * D + d], qb.w, qt3);
      }
      qtil[idx] = ((qt0 + qt1) + (qt2 + qt3)) * SCK;
      float ca = wredsum(bk[d] * qv) * SCK;
      if (d == 0) cvec[b * NSLOT + s] = ca;
    }
    return;
  }

  // ---- mode 1 ----
  float h = 0.f, sl = 0.f;
  if (wv == 0) {
    const float* up = Up + (size_t)(b * NSLOT + s) * NP * D + d;
    float acc = 0.f;
    #pragma unroll
    for (int p = 0; p < NP; ++p) acc += up[p * D];
    const float* sp = Sp + (b * NSLOT + s) * NP;
    float ss = 0.f;
    #pragma unroll
    for (int p = 0; p < NP; ++p) ss += sp[p];
    bufA[d] = acc / ss;
    h = slots[idx];
    bufH[d] = h;
  }
  __syncthreads();
  if (wv == 0) matvec_pre<192>(G,   bufA, gi, d);
  else         matvec_pre<192>(Whh, bufH, gh, d);
  __syncthreads();
  if (wv == 0) {
    float r  = 1.f / (1.f + expf(-(gi[d]        + bias_i[d]        + gh[d]        + bhh[d])));
    float z  = 1.f / (1.f + expf(-(gi[64 + d]   + bias_i[64 + d]   + gh[64 + d]   + bhh[64 + d])));
    float nn = tanhf(gi[128 + d] + bias_i[128 + d] + r * (gh[128 + d] + bhh[128 + d]));
    h = (1.f - z) * nn + z * h;
    float m  = wredsum(h) * (1.f / 64.f);
    float hc = h - m;
    float v  = wredsum(hc * hc) * (1.f / 64.f);
    sl = hc * rsqrtf(v + EPS);
    bufA[d] = sl;
  }
  __syncthreads();
  matvec_pre<64>(W1 + wv * 64 * 64, bufA, gi + wv * 64, d);
  __syncthreads();
  bufH[threadIdx.x] = fmaxf(gi[threadIdx.x] + b1[threadIdx.x], 0.f);
  __syncthreads();
  matvec_pre_c128<32>(W2 + wv * 32 * 128, bufH, gh + wv * 32, d);
  __syncthreads();
  if (wv == 0) {
    h = sl + gh[d] + b2[d];
    slots[idx] = h;
    if (last) out[idx] = h;
  }

  if (!last) {
    if (wv == 0) {
      float m  = wredsum(h) * (1.f / 64.f);
      float hc = h - m;
      float v  = wredsum(hc * hc) * (1.f / 64.f);
      float ln = hc * rsqrtf(v + EPS);
      bufA[d] = ln;
    }
    __syncthreads();
    matvec_pre<32>(Mt + wv * 32 * 64, bufA, gi + wv * 32, d);
    __syncthreads();
    if (wv == 0) {
      qtil[idx] = SCK * (gi[d] + ct[d]);
      float ca = (wredsum(u[d] * bufA[d]) + c0[0]) * SCK;
      if (d == 0) cvec[b * NSLOT + s] = ca;
    }
  }
}

// ---------------------------------------------------------------------------
extern "C" void kernel_launch(void* const* d_in, const int* in_sizes, int n_in,
                              void* d_out, int out_size, void* d_ws, size_t ws_size,
                              hipStream_t stream) {
  (void)in_sizes; (void)n_in; (void)out_size;
  const float* x     = (const float*)d_in[0];
  const float* noise = (const float*)d_in[1];
  const float* Wq    = (const float*)d_in[2];
  const float* bq    = (const float*)d_in[3];
  const float* Wk    = (const float*)d_in[4];
  const float* bk    = (const float*)d_in[5];
  const float* Wv    = (const float*)d_in[6];
  const float* bv    = (const float*)d_in[7];
  const float* Wih   = (const float*)d_in[8];
  const float* Whh   = (const float*)d_in[9];
  const float* bih   = (const float*)d_in[10];
  const float* bhh   = (const float*)d_in[11];
  const float* W1    = (const float*)d_in[12];
  const float* b1    = (const float*)d_in[13];
  const float* W2    = (const float*)d_in[14];
  const float* b2    = (const float*)d_in[15];
  const float* mu    = (const float*)d_in[16];
  const float* sigma = (const float*)d_in[17];

  float* ws     = (float*)d_ws;
  float* slots  = ws;           // 32768
  float* qtil   = ws + 32768;   // 32768
  float* cvec   = ws + 65536;   // 512
  float* Mt     = ws + 66048;   // 4096
  float* ct     = ws + 70144;   // 64
  float* uvec   = ws + 70208;   // 64
  float* c0     = ws + 70272;   // 16 (padded)
  float* G      = ws + 70288;   // 12288
  float* bias_i = ws + 82576;   // 192
  float* Up     = ws + 82768;   // 524288
  float* Sp     = ws + 607056;  // 8192 -> end 615248
  ushortt* xnb  = (ushortt*)(ws + 615296);  // 16.78M shorts = 33.5 MB
  float* out    = (float*)d_out;

  const bool use_xnb = ws_size >= (size_t)(615296 + 8388608) * sizeof(float);

  const int SM1 = 52352;  // Xdr+sA+lU+lS+Xrd
  const int SM2 = 33920;  // Xdr+sA+lU+lS

  auto launch_kb = [&](int mode, int last, int nblk) {
    kb_kernel<<<nblk, 128, 0, stream>>>(mode, last, noise, mu, sigma,
                                        Wq, bq, Wk, bk, Wv, bv, Wih, bih,
                                        G, bias_i, Whh, bhh, W1, b1, W2, b2,
                                        Mt, ct, uvec, c0,
                                        slots, qtil, cvec, Up, Sp, out);
  };

  launch_kb(0, 0, NB * NSLOT + 4);  // init + q~ (unfolded) + prep blocks
  for (int it = 1; it <= 3; ++it) {
    if (!use_xnb) {
      kam_kernel<1><<<NB * NP, 256, SM1, stream>>>(x, xnb, 0, qtil, cvec, Up, Sp);
    } else if (it == 1) {
      kam_kernel<1><<<NB * NP, 256, SM1, stream>>>(x, xnb, 1, qtil, cvec, Up, Sp);
    } else {
      kam_kernel<2><<<NB * NP, 256, SM2, stream>>>(x, xnb, 0, qtil, cvec, Up, Sp);
    }
    launch_kb(1, it == 3 ? 1 : 0, NB * NSLOT);
  }
}

// Round 14
// 116.774 us; speedup vs baseline: 4.5975x; 1.0487x over previous
//
#include <hip/hip_runtime.h>
#include <math.h>

#define D     64
#define NSLOT 8
#define NB    64
#define NROW  4096
#define NP    16          // row-blocks (partials) per batch
#define EPS   1e-5f
#define SCK   (0.125f * 1.44269504f)   // 1/sqrt(64) * 1/ln2 folded into q~ and c

typedef unsigned short ushortt;
typedef __attribute__((ext_vector_type(8))) short bf16x8;
typedef __attribute__((ext_vector_type(4))) float f32x4;

__device__ __forceinline__ unsigned short f2bf(float f) {
  return (unsigned short)((__float_as_uint(f) + 0x8000u) >> 16);
}
__device__ __forceinline__ float bf2f(unsigned short v) {
  return __uint_as_float((unsigned)v << 16);
}

__device__ __forceinline__ float wredsum(float v) {
  #pragma unroll
  for (int m = 1; m < 64; m <<= 1) v += __shfl_xor(v, m);
  return v;
}

// Coalesced wave matvec, full register preload: out[r] = W[r,:].lin, C=64.
template <int R>
__device__ __forceinline__ void matvec_pre(const float* __restrict__ W,
                                           const float* lin, float* lout,
                                           int lane) {
  const int g = lane >> 4, q = lane & 15;
  float4 w[R >> 2];
  #pragma unroll
  for (int rb = 0; rb < (R >> 2); ++rb)
    w[rb] = *reinterpret_cast<const float4*>(W + (rb * 4 + g) * 64 + 4 * q);
  const float4 iv = *reinterpret_cast<const float4*>(lin + 4 * q);
  #pragma unroll
  for (int rb = 0; rb < (R >> 2); ++rb) {
    float p = w[rb].x * iv.x + w[rb].y * iv.y + w[rb].z * iv.z + w[rb].w * iv.w;
    p += __shfl_xor(p, 1);
    p += __shfl_xor(p, 2);
    p += __shfl_xor(p, 4);
    p += __shfl_xor(p, 8);
    if (q == 0) lout[rb * 4 + g] = p;
  }
}

template <int R>
__device__ __forceinline__ void matvec_pre_c128(const float* __restrict__ W,
                                                const float* lin, float* lout,
                                                int lane) {
  const int g = lane >> 4, q = lane & 15;
  float4 w0[R >> 2], w1[R >> 2];
  #pragma unroll
  for (int rb = 0; rb < (R >> 2); ++rb) {
    w0[rb] = *reinterpret_cast<const float4*>(W + (rb * 4 + g) * 128 + 4 * q);
    w1[rb] = *reinterpret_cast<const float4*>(W + (rb * 4 + g) * 128 + 64 + 4 * q);
  }
  const float4 iv0 = *reinterpret_cast<const float4*>(lin + 4 * q);
  const float4 iv1 = *reinterpret_cast<const float4*>(lin + 64 + 4 * q);
  #pragma unroll
  for (int rb = 0; rb < (R >> 2); ++rb) {
    float p = w0[rb].x * iv0.x + w0[rb].y * iv0.y + w0[rb].z * iv0.z + w0[rb].w * iv0.w
            + w1[rb].x * iv1.x + w1[rb].y * iv1.y + w1[rb].z * iv1.z + w1[rb].w * iv1.w;
    p += __shfl_xor(p, 1);
    p += __shfl_xor(p, 2);
    p += __shfl_xor(p, 4);
    p += __shfl_xor(p, 8);
    if (q == 0) lout[rb * 4 + g] = p;
  }
}

// ---------------------------------------------------------------------------
// KAM: MFMA pass over x (r11 body; r13 prefetch reverted — neutral).
// r14 change: PASS=1 LN is fragment-native. Lane (g,sl) loads the 16 elems
// of row h*16+sl at d = kh*32+g*8..+8 (4x float4, 16B-granular coalesced);
// row stats reduce over lanes {sl+16g} -> 2 shfl_xor rounds (vs 16-lane
// butterfly x8 rows); xn lands directly in B-fragment layout -> Xrd LDS
// staging deleted (LDS 52.3 -> 33.9 KB, 4 blocks/CU).
// ---------------------------------------------------------------------------
template <int PASS>
__global__ __launch_bounds__(256)
void kam_kernel(const float* __restrict__ x,
                ushortt* __restrict__ xnb, int store,
                const float* __restrict__ qtil,
                const float* __restrict__ cvec,
                float* __restrict__ Up, float* __restrict__ Sp) {
  extern __shared__ char smem[];
  const int b    = blockIdx.x >> 4;
  const int rb   = blockIdx.x & 15;
  const int tid  = threadIdx.x;
  const int w    = tid >> 6;
  const int lane = tid & 63;
  const int sl   = lane & 15;
  const int g    = lane >> 4;

  short* Xdr = (short*)smem + w * (64 * 40);             // [d][r], stride 40
  short* sA  = (short*)(smem + 20480) + w * (16 * 40);   // [s][r], stride 40
  float* lU  = (float*)(smem + 25600);                   // [4][8][64]
  float* lS  = (float*)(smem + 33792);                   // [4][8]

  // zero sA once: rows s=8..15 stay zero (A-operand padding)
  #pragma unroll
  for (int k = 0; k < 10; ++k) sA[k * 64 + lane] = 0;

  // q~ A-fragments (bf16; slots 8..15 zero). A[m][k]: m=lane&15, k=(lane>>4)*8+j
  bf16x8 qA[2];
  #pragma unroll
  for (int kh = 0; kh < 2; ++kh) {
    if (sl < 8) {
      const float* qp = qtil + (size_t)(b * NSLOT + sl) * D + kh * 32 + g * 8;
      #pragma unroll
      for (int j = 0; j < 8; ++j) qA[kh][j] = (short)f2bf(qp[j]);
    } else {
      #pragma unroll
      for (int j = 0; j < 8; ++j) qA[kh][j] = 0;
    }
  }
  float creg[4];
  #pragma unroll
  for (int r = 0; r < 4; ++r)
    creg[r] = (g < 2) ? cvec[b * NSLOT + 4 * g + r] : 0.f;

  f32x4 C[4];
  #pragma unroll
  for (int nt = 0; nt < 4; ++nt) C[nt] = (f32x4){0.f, 0.f, 0.f, 0.f};
  float Sa[4] = {0.f, 0.f, 0.f, 0.f};

  #pragma unroll
  for (int t = 0; t < 2; ++t) {
    const int tileIdx = (b * NP + rb) * 8 + w * 2 + t;   // 32-row tiles, global id
    bf16x8 Bx[2][2];

    if (PASS == 1) {
      const int rowbase = b * NROW + rb * 256 + w * 64 + t * 32;
      #pragma unroll
      for (int h = 0; h < 2; ++h) {
        // lane (g,sl): row h*16+sl, d = kh*32 + g*8 + {0..7}
        const float* rp = x + (size_t)(rowbase + h * 16 + sl) * 64 + g * 8;
        float4 v00 = *reinterpret_cast<const float4*>(rp);
        float4 v01 = *reinterpret_cast<const float4*>(rp + 4);
        float4 v10 = *reinterpret_cast<const float4*>(rp + 32);
        float4 v11 = *reinterpret_cast<const float4*>(rp + 36);
        float s1 = (v00.x + v00.y + v00.z + v00.w) + (v01.x + v01.y + v01.z + v01.w)
                 + (v10.x + v10.y + v10.z + v10.w) + (v11.x + v11.y + v11.z + v11.w);
        float s2 = v00.x * v00.x + v00.y * v00.y + v00.z * v00.z + v00.w * v00.w
                 + v01.x * v01.x + v01.y * v01.y + v01.z * v01.z + v01.w * v01.w
                 + v10.x * v10.x + v10.y * v10.y + v10.z * v10.z + v10.w * v10.w
                 + v11.x * v11.x + v11.y * v11.y + v11.z * v11.z + v11.w * v11.w;
        s1 += __shfl_xor(s1, 16);
        s1 += __shfl_xor(s1, 32);
        s2 += __shfl_xor(s2, 16);
        s2 += __shfl_xor(s2, 32);
        float mean = s1 * (1.f / 64.f);
        float var  = s2 * (1.f / 64.f) - mean * mean;
        float rstd = rsqrtf(var + EPS);
        float nb   = -mean * rstd;
        Bx[h][0][0] = (short)f2bf(fmaf(v00.x, rstd, nb));
        Bx[h][0][1] = (short)f2bf(fmaf(v00.y, rstd, nb));
        Bx[h][0][2] = (short)f2bf(fmaf(v00.z, rstd, nb));
        Bx[h][0][3] = (short)f2bf(fmaf(v00.w, rstd, nb));
        Bx[h][0][4] = (short)f2bf(fmaf(v01.x, rstd, nb));
        Bx[h][0][5] = (short)f2bf(fmaf(v01.y, rstd, nb));
        Bx[h][0][6] = (short)f2bf(fmaf(v01.z, rstd, nb));
        Bx[h][0][7] = (short)f2bf(fmaf(v01.w, rstd, nb));
        Bx[h][1][0] = (short)f2bf(fmaf(v10.x, rstd, nb));
        Bx[h][1][1] = (short)f2bf(fmaf(v10.y, rstd, nb));
        Bx[h][1][2] = (short)f2bf(fmaf(v10.z, rstd, nb));
        Bx[h][1][3] = (short)f2bf(fmaf(v10.w, rstd, nb));
        Bx[h][1][4] = (short)f2bf(fmaf(v11.x, rstd, nb));
        Bx[h][1][5] = (short)f2bf(fmaf(v11.y, rstd, nb));
        Bx[h][1][6] = (short)f2bf(fmaf(v11.z, rstd, nb));
        Bx[h][1][7] = (short)f2bf(fmaf(v11.w, rstd, nb));
        if (store) {
          #pragma unroll
          for (int kh = 0; kh < 2; ++kh)
            reinterpret_cast<bf16x8*>(xnb)[((size_t)tileIdx * 4 + h * 2 + kh) * 64 + lane] =
                Bx[h][kh];
        }
      }
    } else {
      #pragma unroll
      for (int h = 0; h < 2; ++h)
        #pragma unroll
        for (int kh = 0; kh < 2; ++kh)
          Bx[h][kh] = reinterpret_cast<const bf16x8*>(
              xnb)[((size_t)tileIdx * 4 + h * 2 + kh) * 64 + lane];
    }

    // scatter xn -> Xdr [d][r]  (lane holds row h*16+sl, d = kh*32+g*8+j)
    #pragma unroll
    for (int h = 0; h < 2; ++h)
      #pragma unroll
      for (int kh = 0; kh < 2; ++kh)
        #pragma unroll
        for (int j = 0; j < 8; ++j)
          Xdr[(kh * 32 + g * 8 + j) * 40 + h * 16 + sl] = Bx[h][kh][j];

    // logits + softmax + attn^T pack, per 16-row half
    #pragma unroll
    for (int h = 0; h < 2; ++h) {
      f32x4 Dh = (f32x4){0.f, 0.f, 0.f, 0.f};
      Dh = __builtin_amdgcn_mfma_f32_16x16x32_bf16(qA[0], Bx[h][0], Dh, 0, 0, 0);
      Dh = __builtin_amdgcn_mfma_f32_16x16x32_bf16(qA[1], Bx[h][1], Dh, 0, 0, 0);
      // lane: row r = sl, slots s = 4*g+reg (valid g<2). log2-domain, no max-sub.
      float e[4];
      float z = 0.f;
      #pragma unroll
      for (int r = 0; r < 4; ++r) {
        e[r] = (g < 2) ? exp2f(Dh[r] + creg[r]) : 0.f;
        z += e[r];
      }
      z += __shfl_xor(z, 16);   // combine slot-groups 0+1
      float inv = 1.f / z;
      #pragma unroll
      for (int r = 0; r < 4; ++r) {
        float a = e[r] * inv + 1e-8f;
        unsigned short ab = f2bf(a);
        Sa[r] += bf2f(ab);      // same rounded value as used in MFMA
        if (g < 2) sA[(4 * g + r) * 40 + h * 16 + sl] = (short)ab;
      }
    }

    // update MFMAs: A = attn^T [s][r], B = Xn [r][d]
    bf16x8 aF = *reinterpret_cast<bf16x8*>(&sA[sl * 40 + g * 8]);
    #pragma unroll
    for (int nt = 0; nt < 4; ++nt) {
      bf16x8 bF = *reinterpret_cast<bf16x8*>(&Xdr[(nt * 16 + sl) * 40 + g * 8]);
      C[nt] = __builtin_amdgcn_mfma_f32_16x16x32_bf16(aF, bF, C[nt], 0, 0, 0);
    }
  }

  // epilogue: D[m=s][n=d]: lane holds d = nt*16+sl, s = 4*g+reg (valid g<2)
  if (g < 2) {
    #pragma unroll
    for (int nt = 0; nt < 4; ++nt)
      #pragma unroll
      for (int r = 0; r < 4; ++r)
        lU[(w * NSLOT + 4 * g + r) * D + nt * 16 + sl] = C[nt][r];
  }
  #pragma unroll
  for (int r = 0; r < 4; ++r) {
    #pragma unroll
    for (int m = 1; m < 16; m <<= 1) Sa[r] += __shfl_xor(Sa[r], m);
  }
  if (g < 2 && sl == 0) {
    #pragma unroll
    for (int r = 0; r < 4; ++r) lS[w * NSLOT + 4 * g + r] = Sa[r];
  }
  __syncthreads();

  for (int cell = tid; cell < NSLOT * D; cell += 256) {
    int s = cell >> 6, d = cell & 63;
    Up[((size_t)(b * NSLOT + s) * NP + rb) * D + d] =
        lU[(0 * NSLOT + s) * D + d] + lU[(1 * NSLOT + s) * D + d] +
        lU[(2 * NSLOT + s) * D + d] + lU[(3 * NSLOT + s) * D + d];
  }
  if (tid < NSLOT)
    Sp[(b * NSLOT + tid) * NP + rb] =
        lS[0 * NSLOT + tid] + lS[1 * NSLOT + tid] +
        lS[2 * NSLOT + tid] + lS[3 * NSLOT + tid];
}

// ---------------------------------------------------------------------------
// prep work (4 blocks of 128 thr, appended to the mode-0 kb launch)
// ---------------------------------------------------------------------------
__device__ void prep_block(int pb,
                           const float* __restrict__ Wq, const float* __restrict__ bq,
                           const float* __restrict__ Wk, const float* __restrict__ bk,
                           const float* __restrict__ Wv, const float* __restrict__ bv,
                           const float* __restrict__ Wih, const float* __restrict__ bih,
                           float* __restrict__ Mt, float* __restrict__ ct,
                           float* __restrict__ u, float* __restrict__ c0,
                           float* __restrict__ G, float* __restrict__ bias_i) {
  const int t = threadIdx.x;  // 0..127
  float acc[32];
  #pragma unroll
  for (int j = 0; j < 32; ++j) acc[j] = 0.f;
  if (pb == 0) {
    const int row = t >> 1;
    const int cb  = (t & 1) * 32;
    for (int f = 0; f < 64; ++f) {
      float wkf = Wk[f * 64 + row];
      const float4* wq4 = reinterpret_cast<const float4*>(Wq + f * 64 + cb);
      #pragma unroll
      for (int j4 = 0; j4 < 8; ++j4) {
        float4 wq = wq4[j4];
        acc[4 * j4 + 0] = fmaf(wkf, wq.x, acc[4 * j4 + 0]);
        acc[4 * j4 + 1] = fmaf(wkf, wq.y, acc[4 * j4 + 1]);
        acc[4 * j4 + 2] = fmaf(wkf, wq.z, acc[4 * j4 + 2]);
        acc[4 * j4 + 3] = fmaf(wkf, wq.w, acc[4 * j4 + 3]);
      }
    }
    #pragma unroll
    for (int j = 0; j < 32; ++j) Mt[row * 64 + cb + j] = acc[j];
    if (t < 64) {
      float a = 0.f, bsum = 0.f;
      for (int f = 0; f < 64; ++f) {
        a    = fmaf(bq[f], Wk[f * 64 + t], a);
        bsum = fmaf(bk[f], Wq[f * 64 + t], bsum);
      }
      ct[t] = a;
      u[t]  = bsum;
    }
    if (t == 0) {
      float a = 0.f;
      for (int f = 0; f < 64; ++f) a = fmaf(bk[f], bq[f], a);
      c0[0] = a;
    }
  } else {
    const int r0  = (pb - 1) * 64;
    const int row = r0 + (t >> 1);
    const int cb  = (t & 1) * 32;
    for (int f = 0; f < 64; ++f) {
      float wih = Wih[row * 64 + f];
      const float4* wv4 = reinterpret_cast<const float4*>(Wv + f * 64 + cb);
      #pragma unroll
      for (int j4 = 0; j4 < 8; ++j4) {
        float4 wv = wv4[j4];
        acc[4 * j4 + 0] = fmaf(wih, wv.x, acc[4 * j4 + 0]);
        acc[4 * j4 + 1] = fmaf(wih, wv.y, acc[4 * j4 + 1]);
        acc[4 * j4 + 2] = fmaf(wih, wv.z, acc[4 * j4 + 2]);
        acc[4 * j4 + 3] = fmaf(wih, wv.w, acc[4 * j4 + 3]);
      }
    }
    #pragma unroll
    for (int j = 0; j < 32; ++j) G[row * 64 + cb + j] = acc[j];
    if (t < 64) {
      int rr = r0 + t;
      float a = bih[rr];
      for (int f = 0; f < 64; ++f) a = fmaf(Wih[rr * 64 + f], bv[f], a);
      bias_i[rr] = a;
    }
  }
}

// ---------------------------------------------------------------------------
// KB: per-(batch,slot), 128 threads = 2 waves (unchanged from r11).
// ---------------------------------------------------------------------------
__global__ __launch_bounds__(128, 1)
void kb_kernel(int mode, int last,
               const float* __restrict__ noise, const float* __restrict__ mu,
               const float* __restrict__ sigma,
               const float* __restrict__ Wq, const float* __restrict__ bq,
               const float* __restrict__ Wk, const float* __restrict__ bk,
               const float* __restrict__ Wv, const float* __restrict__ bv,
               const float* __restrict__ Wih, const float* __restrict__ bih,
               float* __restrict__ G, float* __restrict__ bias_i,
               const float* __restrict__ Whh, const float* __restrict__ bhh,
               const float* __restrict__ W1, const float* __restrict__ b1,
               const float* __restrict__ W2, const float* __restrict__ b2,
               float* __restrict__ Mt, float* __restrict__ ct,
               float* __restrict__ u, float* __restrict__ c0,
               float* __restrict__ slots, float* __restrict__ qtil,
               float* __restrict__ cvec, const float* __restrict__ Up,
               const float* __restrict__ Sp, float* __restrict__ out) {
  if (blockIdx.x >= NB * NSLOT) {  // prep blocks (mode-0 launch only)
    prep_block(blockIdx.x - NB * NSLOT, Wq, bq, Wk, bk, Wv, bv, Wih, bih,
               Mt, ct, u, c0, G, bias_i);
    return;
  }

  const int blk = blockIdx.x;
  const int b   = blk >> 3;
  const int s   = blk & 7;
  const int wv  = threadIdx.x >> 6;
  const int d   = threadIdx.x & 63;
  const int idx = (b * NSLOT + s) * D + d;

  __shared__ float bufA[64];
  __shared__ float bufQ[64];
  __shared__ float gi[192];
  __shared__ float gh[192];
  __shared__ float bufH[128];

  if (mode == 0) {
    if (wv == 0) {
      float h = mu[d] + sigma[d] * noise[idx];
      slots[idx] = h;
      float m  = wredsum(h) * (1.f / 64.f);
      float hc = h - m;
      float v  = wredsum(hc * hc) * (1.f / 64.f);
      float ln = hc * rsqrtf(v + EPS);
      bufA[d] = ln;
      matvec_pre<64>(Wq, bufA, gi, d);
      float qv = gi[d] + bq[d];
      bufQ[d] = qv;
      float qt0 = 0.f, qt1 = 0.f, qt2 = 0.f, qt3 = 0.f;
      #pragma unroll
      for (int e = 0; e < 64; e += 4) {
        const float4 qb = *reinterpret_cast<const float4*>(bufQ + e);
        qt0 = fmaf(Wk[(e + 0) * D + d], qb.x, qt0);
        qt1 = fmaf(Wk[(e + 1) * D + d], qb.y, qt1);
        qt2 = fmaf(Wk[(e + 2) * D + d], qb.z, qt2);
        qt3 = fmaf(Wk[(e + 3) * D + d], qb.w, qt3);
      }
      qtil[idx] = ((qt0 + qt1) + (qt2 + qt3)) * SCK;
      float ca = wredsum(bk[d] * qv) * SCK;
      if (d == 0) cvec[b * NSLOT + s] = ca;
    }
    return;
  }

  // ---- mode 1 ----
  float h = 0.f, sl = 0.f;
  if (wv == 0) {
    const float* up = Up + (size_t)(b * NSLOT + s) * NP * D + d;
    float acc = 0.f;
    #pragma unroll
    for (int p = 0; p < NP; ++p) acc += up[p * D];
    const float* sp = Sp + (b * NSLOT + s) * NP;
    float ss = 0.f;
    #pragma unroll
    for (int p = 0; p < NP; ++p) ss += sp[p];
    bufA[d] = acc / ss;
    h = slots[idx];
    bufH[d] = h;
  }
  __syncthreads();
  if (wv == 0) matvec_pre<192>(G,   bufA, gi, d);
  else         matvec_pre<192>(Whh, bufH, gh, d);
  __syncthreads();
  if (wv == 0) {
    float r  = 1.f / (1.f + expf(-(gi[d]        + bias_i[d]        + gh[d]        + bhh[d])));
    float z  = 1.f / (1.f + expf(-(gi[64 + d]   + bias_i[64 + d]   + gh[64 + d]   + bhh[64 + d])));
    float nn = tanhf(gi[128 + d] + bias_i[128 + d] + r * (gh[128 + d] + bhh[128 + d]));
    h = (1.f - z) * nn + z * h;
    float m  = wredsum(h) * (1.f / 64.f);
    float hc = h - m;
    float v  = wredsum(hc * hc) * (1.f / 64.f);
    sl = hc * rsqrtf(v + EPS);
    bufA[d] = sl;
  }
  __syncthreads();
  matvec_pre<64>(W1 + wv * 64 * 64, bufA, gi + wv * 64, d);
  __syncthreads();
  bufH[threadIdx.x] = fmaxf(gi[threadIdx.x] + b1[threadIdx.x], 0.f);
  __syncthreads();
  matvec_pre_c128<32>(W2 + wv * 32 * 128, bufH, gh + wv * 32, d);
  __syncthreads();
  if (wv == 0) {
    h = sl + gh[d] + b2[d];
    slots[idx] = h;
    if (last) out[idx] = h;
  }

  if (!last) {
    if (wv == 0) {
      float m  = wredsum(h) * (1.f / 64.f);
      float hc = h - m;
      float v  = wredsum(hc * hc) * (1.f / 64.f);
      float ln = hc * rsqrtf(v + EPS);
      bufA[d] = ln;
    }
    __syncthreads();
    matvec_pre<32>(Mt + wv * 32 * 64, bufA, gi + wv * 32, d);
    __syncthreads();
    if (wv == 0) {
      qtil[idx] = SCK * (gi[d] + ct[d]);
      float ca = (wredsum(u[d] * bufA[d]) + c0[0]) * SCK;
      if (d == 0) cvec[b * NSLOT + s] = ca;
    }
  }
}

// ---------------------------------------------------------------------------
extern "C" void kernel_launch(void* const* d_in, const int* in_sizes, int n_in,
                              void* d_out, int out_size, void* d_ws, size_t ws_size,
                              hipStream_t stream) {
  (void)in_sizes; (void)n_in; (void)out_size;
  const float* x     = (const float*)d_in[0];
  const float* noise = (const float*)d_in[1];
  const float* Wq    = (const float*)d_in[2];
  const float* bq    = (const float*)d_in[3];
  const float* Wk    = (const float*)d_in[4];
  const float* bk    = (const float*)d_in[5];
  const float* Wv    = (const float*)d_in[6];
  const float* bv    = (const float*)d_in[7];
  const float* Wih   = (const float*)d_in[8];
  const float* Whh   = (const float*)d_in[9];
  const float* bih   = (const float*)d_in[10];
  const float* bhh   = (const float*)d_in[11];
  const float* W1    = (const float*)d_in[12];
  const float* b1    = (const float*)d_in[13];
  const float* W2    = (const float*)d_in[14];
  const float* b2    = (const float*)d_in[15];
  const float* mu    = (const float*)d_in[16];
  const float* sigma = (const float*)d_in[17];

  float* ws     = (float*)d_ws;
  float* slots  = ws;           // 32768
  float* qtil   = ws + 32768;   // 32768
  float* cvec   = ws + 65536;   // 512
  float* Mt     = ws + 66048;   // 4096
  float* ct     = ws + 70144;   // 64
  float* uvec   = ws + 70208;   // 64
  float* c0     = ws + 70272;   // 16 (padded)
  float* G      = ws + 70288;   // 12288
  float* bias_i = ws + 82576;   // 192
  float* Up     = ws + 82768;   // 524288
  float* Sp     = ws + 607056;  // 8192 -> end 615248
  ushortt* xnb  = (ushortt*)(ws + 615296);  // 16.78M shorts = 33.5 MB
  float* out    = (float*)d_out;

  const bool use_xnb = ws_size >= (size_t)(615296 + 8388608) * sizeof(float);

  const int SM = 33920;  // Xdr+sA+lU+lS (Xrd eliminated)

  auto launch_kb = [&](int mode, int last, int nblk) {
    kb_kernel<<<nblk, 128, 0, stream>>>(mode, last, noise, mu, sigma,
                                        Wq, bq, Wk, bk, Wv, bv, Wih, bih,
                                        G, bias_i, Whh, bhh, W1, b1, W2, b2,
                                        Mt, ct, uvec, c0,
                                        slots, qtil, cvec, Up, Sp, out);
  };

  launch_kb(0, 0, NB * NSLOT + 4);  // init + q~ (unfolded) + prep blocks
  for (int it = 1; it <= 3; ++it) {
    if (!use_xnb) {
      kam_kernel<1><<<NB * NP, 256, SM, stream>>>(x, xnb, 0, qtil, cvec, Up, Sp);
    } else if (it == 1) {
      kam_kernel<1><<<NB * NP, 256, SM, stream>>>(x, xnb, 1, qtil, cvec, Up, Sp);
    } else {
      kam_kernel<2><<<NB * NP, 256, SM, stream>>>(x, xnb, 0, qtil, cvec, Up, Sp);
    }
    launch_kb(1, it == 3 ? 1 : 0, NB * NSLOT);
  }
}